// Round 7
// baseline (1017.048 us; speedup 1.0000x reference)
//
#include <hip/hip_runtime.h>
#include <cstddef>

// Problem dims
#define BATCH 64
#define SEQ   256
#define VOCAB 50000
#define DIM   300
#define NW    8192
#define CLEN  16
#define CDIM  30
#define CHC   30
#define HID   128
#define NT    17
#define IN0   (DIM + CHC)   // 330
#define IN0P  336           // padded to multiple of 16
#define IN1   (2 * HID)     // 256
#define NPOS  (BATCH * SEQ) // 16384

// Workspace layout (floats)
constexpr size_t SZ_XG    = 2ull * BATCH * SEQ * 384;    // 12,582,912
constexpr size_t SZ_TEXTS = (size_t)NPOS * IN0P;         // 5,505,024 (aliased as h0 after GEMM0)
constexpr size_t SZ_H1    = (size_t)NPOS * 256;          // 4,194,304
constexpr size_t SZ_TOK   = 245792;                      // (NW+1)*30 rounded
constexpr size_t SZ_EMIS  = (size_t)NPOS * NT;           // 278,528
constexpr size_t SZ_WPAD  = 768ull * IN0P;               // 258,048
constexpr size_t OFF_XG    = 0;
constexpr size_t OFF_TEXTS = OFF_XG + SZ_XG;
constexpr size_t OFF_H1    = OFF_TEXTS + SZ_TEXTS;
constexpr size_t OFF_TOK   = OFF_H1 + SZ_H1;
constexpr size_t OFF_EMIS  = OFF_TOK + SZ_TOK;
constexpr size_t OFF_WPAD  = OFF_EMIS + SZ_EMIS;
constexpr size_t OFF_LLH   = OFF_WPAD + SZ_WPAD;

__device__ __forceinline__ float sigm(float x) {
    return 1.f / (1.f + __expf(-x));
}
__device__ __forceinline__ float tanh_fast(float x) {
    x = fminf(fmaxf(x, -15.f), 15.f);
    float e = __expf(-2.f * x);
    return (1.f - e) / (1.f + e);
}
// Sum across 8 consecutive lanes (i&7 group) using DPP only (VALU pipe; no
// LDS). Stages: xor1, xor2 via quad_perm; xor4 via row_half_mirror (lane
// i reads lane i^7, which after the first two stages carries the other
// quad's full partial sum).
__device__ __forceinline__ float oct_sum(float x) {
    int y = __builtin_amdgcn_update_dpp(0, __float_as_int(x), 0xB1, 0xF, 0xF, false);  // quad_perm [1,0,3,2]
    x += __int_as_float(y);
    y = __builtin_amdgcn_update_dpp(0, __float_as_int(x), 0x4E, 0xF, 0xF, false);      // quad_perm [2,3,0,1]
    x += __int_as_float(y);
    y = __builtin_amdgcn_update_dpp(0, __float_as_int(x), 0x141, 0xF, 0xF, false);     // row_half_mirror
    x += __int_as_float(y);
    return x;
}

// ---------------- K1: char CNN + relu + maxpool -> tok_enc[(n+1)][30] ----
__global__ __launch_bounds__(256) void char_conv_k(
    const float* __restrict__ char_emb,  // [500][30]
    const float* __restrict__ conv_w,    // [30][30][3]
    const float* __restrict__ conv_b,    // [30]
    const int*   __restrict__ words,     // [8192][16]
    float* __restrict__ tok_enc)         // [8193][30]
{
    __shared__ __align__(16) float cs[8][CLEN][CDIM];
    __shared__ float wsm[CHC * CDIM * 3];
    __shared__ float bs[CHC];
    int n0 = blockIdx.x * 8;
    int tid = threadIdx.x;
    for (int e = tid; e < CHC * CDIM * 3; e += 256) wsm[e] = conv_w[e];
    if (tid < CHC) bs[tid] = conv_b[tid];
    for (int e = tid; e < 8 * CLEN * CDIM; e += 256) {
        int wi = e / (CLEN * CDIM);
        int rem = e - wi * (CLEN * CDIM);
        int l = rem / CDIM;
        int i = rem - l * CDIM;
        int ci = words[(n0 + wi) * CLEN + l];
        cs[wi][l][i] = char_emb[ci * CDIM + i];
    }
    __syncthreads();
    int wi = tid >> 5;
    int o = tid & 31;
    if (o < CHC) {
        float best = -1e30f;
        for (int l = 0; l < CLEN; l++) {
            float s = 0.f;
            #pragma unroll
            for (int k = 0; k < 3; k++) {
                int ll = l + k - 1;
                if (ll >= 0 && ll < CLEN) {
                    #pragma unroll
                    for (int i = 0; i < CDIM; i++)
                        s += cs[wi][ll][i] * wsm[(o * CDIM + i) * 3 + k];
                }
            }
            best = fmaxf(best, s);
        }
        tok_enc[(size_t)(n0 + wi + 1) * CDIM + o] = fmaxf(best + bs[o], 0.f);
    }
}

// ---------------- K2: texts = concat(word_emb[tok], tok_enc[widx]), pad to 336
__global__ __launch_bounds__(128) void build_texts_k(
    const float* __restrict__ word_emb,
    const float* __restrict__ tok_enc,
    const int*   __restrict__ tokens,
    const int*   __restrict__ widx,
    float* __restrict__ texts)
{
    int p = blockIdx.x;
    int tok = tokens[p];
    int ci = widx[p];
    float* o = texts + (size_t)p * IN0P;
    const float* wr = word_emb + (size_t)tok * DIM;
    const float* tr = tok_enc + (size_t)ci * CDIM;
    for (int c = threadIdx.x; c < IN0P; c += 128)
        o[c] = (c < DIM) ? wr[c] : (c < IN0 ? tr[c - DIM] : 0.f);
}

// ---------------- K2b: pad w_ih_l0 (768x330) -> (768x336) ---------------
__global__ __launch_bounds__(64) void pad_w_k(
    const float* __restrict__ w, float* __restrict__ wp)
{
    int r = blockIdx.x;
    for (int c = threadIdx.x; c < IN0P; c += 64)
        wp[(size_t)r * IN0P + c] = (c < IN0) ? w[(size_t)r * IN0 + c] : 0.f;
}

// ---------------- K3/K5: xg = A @ W_ih^T + b_ih, stored [d][b][t][g] -----
// A: [16384][K] row-major (K multiple of 16), W: [768][K] row-major
#define GBM 128
#define GBN 128
#define GBK 16
__global__ __launch_bounds__(256) void gemm_xg_k(
    const float* __restrict__ A,
    const float* __restrict__ W,
    const float* __restrict__ bias,
    float* __restrict__ out,
    int K)
{
    __shared__ __align__(16) float As[GBK][GBM];
    __shared__ __align__(16) float Ws[GBK][GBN];
    int tid = threadIdx.x;
    int m0 = blockIdx.x * GBM;
    int n0 = blockIdx.y * GBN;
    int lrow = tid >> 1;
    int lk = (tid & 1) * 8;
    int ty = tid >> 4;   // 0..15 (m)
    int tx = tid & 15;   // 0..15 (n)

    float acc[8][8];
    #pragma unroll
    for (int i = 0; i < 8; i++)
        #pragma unroll
        for (int j = 0; j < 8; j++) acc[i][j] = 0.f;

    for (int k0 = 0; k0 < K; k0 += GBK) {
        const float4* ap = (const float4*)(A + (size_t)(m0 + lrow) * K + k0 + lk);
        const float4* wp = (const float4*)(W + (size_t)(n0 + lrow) * K + k0 + lk);
        float4 va0 = ap[0], va1 = ap[1];
        float4 vw0 = wp[0], vw1 = wp[1];
        As[lk + 0][lrow] = va0.x; As[lk + 1][lrow] = va0.y;
        As[lk + 2][lrow] = va0.z; As[lk + 3][lrow] = va0.w;
        As[lk + 4][lrow] = va1.x; As[lk + 5][lrow] = va1.y;
        As[lk + 6][lrow] = va1.z; As[lk + 7][lrow] = va1.w;
        Ws[lk + 0][lrow] = vw0.x; Ws[lk + 1][lrow] = vw0.y;
        Ws[lk + 2][lrow] = vw0.z; Ws[lk + 3][lrow] = vw0.w;
        Ws[lk + 4][lrow] = vw1.x; Ws[lk + 5][lrow] = vw1.y;
        Ws[lk + 6][lrow] = vw1.z; Ws[lk + 7][lrow] = vw1.w;
        __syncthreads();
        #pragma unroll
        for (int k = 0; k < GBK; k++) {
            float4 a0 = *(const float4*)&As[k][ty * 8];
            float4 a1 = *(const float4*)&As[k][ty * 8 + 4];
            float4 b0 = *(const float4*)&Ws[k][tx * 8];
            float4 b1 = *(const float4*)&Ws[k][tx * 8 + 4];
            float av[8] = {a0.x, a0.y, a0.z, a0.w, a1.x, a1.y, a1.z, a1.w};
            float bv[8] = {b0.x, b0.y, b0.z, b0.w, b1.x, b1.y, b1.z, b1.w};
            #pragma unroll
            for (int i = 0; i < 8; i++)
                #pragma unroll
                for (int j = 0; j < 8; j++)
                    acc[i][j] += av[i] * bv[j];
        }
        __syncthreads();
    }
    // store to xg layout: ((d*64+b)*256+t)*384 + g
    int nb = n0 + tx * 8;
    int d = nb / 384;
    int g0 = nb - d * 384;
    float bvv[8];
    #pragma unroll
    for (int j = 0; j < 8; j++) bvv[j] = bias[nb + j];
    int mbase = m0 + ty * 8;
    #pragma unroll
    for (int i = 0; i < 8; i++) {
        int m = mbase + i;
        int b = m >> 8;
        int t = m & 255;
        float* op = out + (((size_t)(d * BATCH + b) * SEQ + t) * 384 + g0);
        #pragma unroll
        for (int j = 0; j < 8; j++) op[j] = acc[i][j] + bvv[j];
    }
}

// ---------------- K4/K6: GRU recurrence, one wg per (dir, batch) ---------
// 512 threads, E=2 x 8 k-chunks: thread (e = i>>3 in [0,64), c = i&7) owns
// gate rows {e,128+e,256+e} and {e+64,192+e,320+e}, k-chunk [16c,16c+16).
// 8 waves -> 2 waves/SIMD (the R6 lesson: never drop below 2), LDS pipe
// only 4 ds_read_b128/wave/step = 32/step (half of R5). 8-lane reduction
// entirely in DPP (VALU). Rotation swizzle m=(q+c)&3: banks for c and c+4
// alias 2-way (free), all else disjoint. Single barrier/step, h double-
// buffered, out-store deferred one step, xg prefetched one step ahead.
__global__ __launch_bounds__(512, 1) void gru_rec_k(
    const float* __restrict__ xg,    // [2][64][256][384]
    const float* __restrict__ w_hh,  // [2][384][128]
    const float* __restrict__ b_hh,  // [2][384]
    const int*   __restrict__ lens,  // [64]
    float* __restrict__ out)         // [64][256][256], channel = d*128+j
{
    int d = blockIdx.x & 1;
    int b = blockIdx.x >> 1;
    int i = threadIdx.x;   // 0..511
    int e0 = i >> 3;       // 0..63
    int e1 = e0 + 64;      // 64..127
    int c = i & 7;         // 0..7 k-chunk (16 floats)
    __shared__ __align__(16) float hS[2][HID];

    const float* wb = w_hh + (size_t)d * 384 * HID;
    // Preload weights rotated: iteration q consumes float4 m = (q+c)&3 of
    // this thread's 16-float chunk (chunk base = 16*c floats).
    float4 wR0[4], wZ0[4], wN0[4], wR1[4], wZ1[4], wN1[4];
    #pragma unroll
    for (int q = 0; q < 4; q++) {
        int m = (q + c) & 3;
        int off = 16 * c + 4 * m;
        wR0[q] = *(const float4*)(wb + (size_t)(e0)       * HID + off);
        wZ0[q] = *(const float4*)(wb + (size_t)(128 + e0) * HID + off);
        wN0[q] = *(const float4*)(wb + (size_t)(256 + e0) * HID + off);
        wR1[q] = *(const float4*)(wb + (size_t)(e1)       * HID + off);
        wZ1[q] = *(const float4*)(wb + (size_t)(128 + e1) * HID + off);
        wN1[q] = *(const float4*)(wb + (size_t)(256 + e1) * HID + off);
    }
    float bhR0 = b_hh[d * 384 + e0];
    float bhZ0 = b_hh[d * 384 + 128 + e0];
    float bhN0 = b_hh[d * 384 + 256 + e0];
    float bhR1 = b_hh[d * 384 + e1];
    float bhZ1 = b_hh[d * 384 + 128 + e1];
    float bhN1 = b_hh[d * 384 + 256 + e1];
    int len = lens[b];

    if (i < HID) hS[0][i] = 0.f;
    float hold0 = 0.f, hold1 = 0.f;
    __syncthreads();

    const float* xgb = xg + ((size_t)(d * BATCH + b)) * SEQ * 384;
    float* outb = out + (size_t)b * SEQ * 256 + d * HID;

    int t0 = d ? (SEQ - 1) : 0;
    float xR0 = xgb[(size_t)t0 * 384 + e0];
    float xZ0 = xgb[(size_t)t0 * 384 + 128 + e0];
    float xN0 = xgb[(size_t)t0 * 384 + 256 + e0];
    float xR1 = xgb[(size_t)t0 * 384 + e1];
    float xZ1 = xgb[(size_t)t0 * 384 + 128 + e1];
    float xN1 = xgb[(size_t)t0 * 384 + 256 + e1];
    int tPrev = 0;

    for (int s = 0; s < SEQ; s++) {
        int t = d ? (SEQ - 1 - s) : s;
        // deferred out-store of previous step's h (vmcnt drain hidden
        // behind this step's dot-product work)
        if (s && c == 0) {
            outb[(size_t)tPrev * 256 + e0] = hold0;
            outb[(size_t)tPrev * 256 + e1] = hold1;
        }
        // prefetch next step's xg
        int sn = (s + 1 < SEQ) ? (s + 1) : s;
        int tn = d ? (SEQ - 1 - sn) : sn;
        float nxR0 = xgb[(size_t)tn * 384 + e0];
        float nxZ0 = xgb[(size_t)tn * 384 + 128 + e0];
        float nxN0 = xgb[(size_t)tn * 384 + 256 + e0];
        float nxR1 = xgb[(size_t)tn * 384 + e1];
        float nxZ1 = xgb[(size_t)tn * 384 + 128 + e1];
        float nxN1 = xgb[(size_t)tn * 384 + 256 + e1];

        const float4* hb = (const float4*)hS[s & 1] + 4 * c;
        float sR0 = 0.f, sZ0 = 0.f, sN0 = 0.f;
        float sR1 = 0.f, sZ1 = 0.f, sN1 = 0.f;
        #pragma unroll
        for (int q = 0; q < 4; q++) {
            int m = (q + c) & 3;
            float4 hv = hb[m];
            sR0 += wR0[q].x * hv.x + wR0[q].y * hv.y + wR0[q].z * hv.z + wR0[q].w * hv.w;
            sZ0 += wZ0[q].x * hv.x + wZ0[q].y * hv.y + wZ0[q].z * hv.z + wZ0[q].w * hv.w;
            sN0 += wN0[q].x * hv.x + wN0[q].y * hv.y + wN0[q].z * hv.z + wN0[q].w * hv.w;
            sR1 += wR1[q].x * hv.x + wR1[q].y * hv.y + wR1[q].z * hv.z + wR1[q].w * hv.w;
            sZ1 += wZ1[q].x * hv.x + wZ1[q].y * hv.y + wZ1[q].z * hv.z + wZ1[q].w * hv.w;
            sN1 += wN1[q].x * hv.x + wN1[q].y * hv.y + wN1[q].z * hv.z + wN1[q].w * hv.w;
        }
        sR0 = oct_sum(sR0); sZ0 = oct_sum(sZ0); sN0 = oct_sum(sN0);
        sR1 = oct_sum(sR1); sZ1 = oct_sum(sZ1); sN1 = oct_sum(sN1);

        float r0 = sigm(xR0 + sR0 + bhR0);
        float z0 = sigm(xZ0 + sZ0 + bhZ0);
        float n0 = tanh_fast(xN0 + r0 * (sN0 + bhN0));
        float hnew0 = (1.f - z0) * n0 + z0 * hold0;
        float r1 = sigm(xR1 + sR1 + bhR1);
        float z1 = sigm(xZ1 + sZ1 + bhZ1);
        float n1 = tanh_fast(xN1 + r1 * (sN1 + bhN1));
        float hnew1 = (1.f - z1) * n1 + z1 * hold1;
        bool upd = (t < len);
        hold0 = upd ? hnew0 : hold0;
        hold1 = upd ? hnew1 : hold1;
        if (c == 0) {
            hS[(s & 1) ^ 1][e0] = hold0;
            hS[(s & 1) ^ 1][e1] = hold1;
        }
        tPrev = t;
        xR0 = nxR0; xZ0 = nxZ0; xN0 = nxN0;
        xR1 = nxR1; xZ1 = nxZ1; xN1 = nxN1;
        __syncthreads();
    }
    if (c == 0) {
        outb[(size_t)tPrev * 256 + e0] = hold0;
        outb[(size_t)tPrev * 256 + e1] = hold1;
    }
}

// ---------------- K7: MLP (relu) + emissions -----------------------------
__global__ __launch_bounds__(128) void mlp_emis_k(
    const float* __restrict__ h1,    // [16384][256]
    const float* __restrict__ w1,    // [256][128]
    const float* __restrict__ b1,    // [128]
    const float* __restrict__ w2,    // [128][17]
    const float* __restrict__ b2,    // [17]
    float* __restrict__ emis)        // [16384][17]
{
    __shared__ __align__(16) float hrow[8 * 256];
    __shared__ float hid[8][HID];
    int p0 = blockIdx.x * 8;
    int tid = threadIdx.x;
    for (int e = tid; e < 8 * 256; e += 128)
        hrow[e] = h1[(size_t)p0 * 256 + e];
    __syncthreads();
    float acc[8];
    float bb = b1[tid];
    #pragma unroll
    for (int i = 0; i < 8; i++) acc[i] = bb;
    for (int k = 0; k < 256; k++) {
        float wv = w1[k * HID + tid];
        #pragma unroll
        for (int i = 0; i < 8; i++) acc[i] += hrow[i * 256 + k] * wv;
    }
    #pragma unroll
    for (int i = 0; i < 8; i++) hid[i][tid] = fmaxf(acc[i], 0.f);
    __syncthreads();
    for (int idx = tid; idx < 8 * NT; idx += 128) {
        int pos = idx / NT;
        int tg = idx - pos * NT;
        float a = b2[tg];
        for (int k = 0; k < HID; k++) a += hid[pos][k] * w2[k * NT + tg];
        emis[(size_t)(p0 + pos) * NT + tg] = a;
    }
}

// ---------------- K8: CRF score + forward algorithm ----------------------
__global__ __launch_bounds__(64) void crf_k(
    const float* __restrict__ emis,   // [64][256][17]
    const float* __restrict__ start,
    const float* __restrict__ endv,
    const float* __restrict__ trans,  // [17][17]
    const int*   __restrict__ target, // [64][256]
    const int*   __restrict__ lens,
    float* __restrict__ llh)          // [64]
{
    int b = blockIdx.x;
    int tid = threadIdx.x;
    __shared__ float tr[NT * NT];
    __shared__ float aSh[NT];
    __shared__ float scoreSh;
    for (int e = tid; e < NT * NT; e += 64) tr[e] = trans[e];
    __syncthreads();
    int len = lens[b];
    const int* tgt = target + b * SEQ;
    const float* eb = emis + (size_t)b * SEQ * NT;

    // gold score (parallel over t, reduce in-wave)
    float part = 0.f;
    for (int t = 1 + tid; t < SEQ; t += 64) {
        if (t < len) {
            int tp = tgt[t - 1], tc = tgt[t];
            part += tr[tp * NT + tc] + eb[(size_t)t * NT + tc];
        }
    }
    #pragma unroll
    for (int off = 32; off > 0; off >>= 1)
        part += __shfl_down(part, off, 64);
    if (tid == 0) {
        int t0 = tgt[0];
        scoreSh = part + start[t0] + eb[t0] + endv[tgt[len - 1]];
    }

    // forward algorithm
    float a = (tid < NT) ? (start[tid] + eb[tid]) : 0.f;
    for (int t = 1; t < SEQ; t++) {
        if (tid < NT) aSh[tid] = a;
        __syncthreads();
        if (t < len && tid < NT) {
            float m = -1e30f;
            #pragma unroll
            for (int i = 0; i < NT; i++)
                m = fmaxf(m, aSh[i] + tr[i * NT + tid]);
            float ssum = 0.f;
            #pragma unroll
            for (int i = 0; i < NT; i++)
                ssum += __expf(aSh[i] + tr[i * NT + tid] - m);
            a = m + __logf(ssum) + eb[(size_t)t * NT + tid];
        }
        __syncthreads();
    }
    float v = (tid < NT) ? (a + endv[tid]) : -1e30f;
    float m = v;
    #pragma unroll
    for (int off = 32; off > 0; off >>= 1)
        m = fmaxf(m, __shfl_down(m, off, 64));
    m = __shfl(m, 0, 64);
    float e = (tid < NT) ? __expf(v - m) : 0.f;
    #pragma unroll
    for (int off = 32; off > 0; off >>= 1)
        e += __shfl_down(e, off, 64);
    if (tid == 0) {
        float logz = m + __logf(e);
        llh[b] = scoreSh - logz;
    }
}

// ---------------- K9: final loss -----------------------------------------
__global__ __launch_bounds__(64) void finalize_k(
    const float* __restrict__ llh,
    const int*   __restrict__ lens,
    float* __restrict__ out)
{
    int tid = threadIdx.x;
    float s = llh[tid];
    float lf = (float)lens[tid];
    #pragma unroll
    for (int off = 32; off > 0; off >>= 1) {
        s += __shfl_down(s, off, 64);
        lf += __shfl_down(lf, off, 64);
    }
    if (tid == 0) out[0] = -(s / lf);
}

extern "C" void kernel_launch(void* const* d_in, const int* in_sizes, int n_in,
                              void* d_out, int out_size, void* d_ws, size_t ws_size,
                              hipStream_t stream) {
    const float* char_emb = (const float*)d_in[0];
    const float* conv_w   = (const float*)d_in[1];
    const float* conv_b   = (const float*)d_in[2];
    const float* word_emb = (const float*)d_in[3];
    const float* w_ih_l0  = (const float*)d_in[4];
    const float* w_hh_l0  = (const float*)d_in[5];
    const float* b_ih_l0  = (const float*)d_in[6];
    const float* b_hh_l0  = (const float*)d_in[7];
    const float* w_ih_l1  = (const float*)d_in[8];
    const float* w_hh_l1  = (const float*)d_in[9];
    const float* b_ih_l1  = (const float*)d_in[10];
    const float* b_hh_l1  = (const float*)d_in[11];
    const float* mlp_w1   = (const float*)d_in[12];
    const float* mlp_b1   = (const float*)d_in[13];
    const float* mlp_w2   = (const float*)d_in[14];
    const float* mlp_b2   = (const float*)d_in[15];
    const float* crf_start= (const float*)d_in[16];
    const float* crf_end  = (const float*)d_in[17];
    const float* crf_trans= (const float*)d_in[18];
    const int* bcw   = (const int*)d_in[19];
    // d_in[20] batched_char_words_len: unused by reference
    const int* bcwi  = (const int*)d_in[21];
    const int* btok  = (const int*)d_in[22];
    const int* blen  = (const int*)d_in[23];
    const int* target= (const int*)d_in[24];

    float* ws    = (float*)d_ws;
    float* xg    = ws + OFF_XG;
    float* texts = ws + OFF_TEXTS;   // aliased: h0 overwrites texts after xg0 GEMM
    float* h0    = texts;
    float* h1    = ws + OFF_H1;
    float* tok   = ws + OFF_TOK;
    float* emis  = ws + OFF_EMIS;
    float* wpad  = ws + OFF_WPAD;
    float* llh   = ws + OFF_LLH;

    hipMemsetAsync(tok, 0, CDIM * sizeof(float), stream);  // tok_enc row 0 = zeros
    pad_w_k<<<768, 64, 0, stream>>>(w_ih_l0, wpad);
    char_conv_k<<<NW / 8, 256, 0, stream>>>(char_emb, conv_w, conv_b, bcw, tok);
    build_texts_k<<<NPOS, 128, 0, stream>>>(word_emb, tok, btok, bcwi, texts);
    gemm_xg_k<<<dim3(NPOS / GBM, 768 / GBN), 256, 0, stream>>>(texts, wpad, b_ih_l0, xg, IN0P);
    gru_rec_k<<<2 * BATCH, 512, 0, stream>>>(xg, w_hh_l0, b_hh_l0, blen, h0);
    gemm_xg_k<<<dim3(NPOS / GBM, 768 / GBN), 256, 0, stream>>>(h0, w_ih_l1, b_ih_l1, xg, IN1);
    gru_rec_k<<<2 * BATCH, 512, 0, stream>>>(xg, w_hh_l1, b_hh_l1, blen, h1);
    mlp_emis_k<<<NPOS / 8, 128, 0, stream>>>(h1, mlp_w1, mlp_b1, mlp_w2, mlp_b2, emis);
    crf_k<<<BATCH, 64, 0, stream>>>(emis, crf_start, crf_end, crf_trans, target, blen, llh);
    finalize_k<<<1, 64, 0, stream>>>(llh, blen, (float*)d_out);
}

// Round 8
// 894.249 us; speedup vs baseline: 1.1373x; 1.1373x over previous
//
#include <hip/hip_runtime.h>
#include <cstddef>

// Problem dims
#define BATCH 64
#define SEQ   256
#define VOCAB 50000
#define DIM   300
#define NW    8192
#define CLEN  16
#define CDIM  30
#define CHC   30
#define HID   128
#define NT    17
#define IN0   (DIM + CHC)   // 330
#define IN0P  336           // padded to multiple of 16
#define IN1   (2 * HID)     // 256
#define NPOS  (BATCH * SEQ) // 16384

// Workspace layout (floats)
constexpr size_t SZ_XG    = 2ull * BATCH * SEQ * 384;    // 12,582,912
constexpr size_t SZ_TEXTS = (size_t)NPOS * IN0P;         // 5,505,024 (aliased as h0 after GEMM0)
constexpr size_t SZ_H1    = (size_t)NPOS * 256;          // 4,194,304
constexpr size_t SZ_TOK   = 245792;                      // (NW+1)*30 rounded
constexpr size_t SZ_EMIS  = (size_t)NPOS * NT;           // 278,528
constexpr size_t SZ_WPAD  = 768ull * IN0P;               // 258,048
constexpr size_t OFF_XG    = 0;
constexpr size_t OFF_TEXTS = OFF_XG + SZ_XG;
constexpr size_t OFF_H1    = OFF_TEXTS + SZ_TEXTS;
constexpr size_t OFF_TOK   = OFF_H1 + SZ_H1;
constexpr size_t OFF_EMIS  = OFF_TOK + SZ_TOK;
constexpr size_t OFF_WPAD  = OFF_EMIS + SZ_EMIS;
constexpr size_t OFF_LLH   = OFF_WPAD + SZ_WPAD;

typedef float float2v __attribute__((ext_vector_type(2)));

__device__ __forceinline__ float sigm(float x) {
    return 1.f / (1.f + __expf(-x));
}
__device__ __forceinline__ float tanh_fast(float x) {
    x = fminf(fmaxf(x, -15.f), 15.f);
    float e = __expf(-2.f * x);
    return (1.f - e) / (1.f + e);
}
// Sum across the 4 lanes of a quad using DPP quad_perm (VALU-only; no LDS
// pipe, unlike __shfl which compiles to ds_bpermute).
__device__ __forceinline__ float quad_sum(float x) {
    int y = __builtin_amdgcn_update_dpp(0, __float_as_int(x), 0xB1, 0xF, 0xF, false); // [1,0,3,2]
    x += __int_as_float(y);
    y = __builtin_amdgcn_update_dpp(0, __float_as_int(x), 0x4E, 0xF, 0xF, false);     // [2,3,0,1]
    x += __int_as_float(y);
    return x;
}

// ---------------- K1: char CNN + relu + maxpool -> tok_enc[(n+1)][30] ----
__global__ __launch_bounds__(256) void char_conv_k(
    const float* __restrict__ char_emb,  // [500][30]
    const float* __restrict__ conv_w,    // [30][30][3]
    const float* __restrict__ conv_b,    // [30]
    const int*   __restrict__ words,     // [8192][16]
    float* __restrict__ tok_enc)         // [8193][30]
{
    __shared__ __align__(16) float cs[8][CLEN][CDIM];
    __shared__ float wsm[CHC * CDIM * 3];
    __shared__ float bs[CHC];
    int n0 = blockIdx.x * 8;
    int tid = threadIdx.x;
    for (int e = tid; e < CHC * CDIM * 3; e += 256) wsm[e] = conv_w[e];
    if (tid < CHC) bs[tid] = conv_b[tid];
    for (int e = tid; e < 8 * CLEN * CDIM; e += 256) {
        int wi = e / (CLEN * CDIM);
        int rem = e - wi * (CLEN * CDIM);
        int l = rem / CDIM;
        int i = rem - l * CDIM;
        int ci = words[(n0 + wi) * CLEN + l];
        cs[wi][l][i] = char_emb[ci * CDIM + i];
    }
    __syncthreads();
    int wi = tid >> 5;
    int o = tid & 31;
    if (o < CHC) {
        float best = -1e30f;
        for (int l = 0; l < CLEN; l++) {
            float s = 0.f;
            #pragma unroll
            for (int k = 0; k < 3; k++) {
                int ll = l + k - 1;
                if (ll >= 0 && ll < CLEN) {
                    #pragma unroll
                    for (int i = 0; i < CDIM; i++)
                        s += cs[wi][ll][i] * wsm[(o * CDIM + i) * 3 + k];
                }
            }
            best = fmaxf(best, s);
        }
        tok_enc[(size_t)(n0 + wi + 1) * CDIM + o] = fmaxf(best + bs[o], 0.f);
    }
}

// ---------------- K2: texts = concat(word_emb[tok], tok_enc[widx]), pad to 336
__global__ __launch_bounds__(128) void build_texts_k(
    const float* __restrict__ word_emb,
    const float* __restrict__ tok_enc,
    const int*   __restrict__ tokens,
    const int*   __restrict__ widx,
    float* __restrict__ texts)
{
    int p = blockIdx.x;
    int tok = tokens[p];
    int ci = widx[p];
    float* o = texts + (size_t)p * IN0P;
    const float* wr = word_emb + (size_t)tok * DIM;
    const float* tr = tok_enc + (size_t)ci * CDIM;
    for (int c = threadIdx.x; c < IN0P; c += 128)
        o[c] = (c < DIM) ? wr[c] : (c < IN0 ? tr[c - DIM] : 0.f);
}

// ---------------- K2b: pad w_ih_l0 (768x330) -> (768x336) ---------------
__global__ __launch_bounds__(64) void pad_w_k(
    const float* __restrict__ w, float* __restrict__ wp)
{
    int r = blockIdx.x;
    for (int c = threadIdx.x; c < IN0P; c += 64)
        wp[(size_t)r * IN0P + c] = (c < IN0) ? w[(size_t)r * IN0 + c] : 0.f;
}

// ---------------- K3/K5: xg = A @ W_ih^T + b_ih, stored [d][b][t][g] -----
// A: [16384][K] row-major (K multiple of 16), W: [768][K] row-major
// Ws tile uses a bank-quad swizzle: logical column n stored at physical
// n + 4*((n>>5)&1) (row padded to 132). Read bases become
// 8tx + 4*((tx>>2)&1) -> {0,8,16,24,4,12,20,28} mod 32 = all 8 bank quads,
// killing the 4-way ds_read_b128 conflict of the naive {0,8,16,24} pattern.
#define GBM 128
#define GBN 128
#define GBK 16
#define GBNP 132
__global__ __launch_bounds__(256) void gemm_xg_k(
    const float* __restrict__ A,
    const float* __restrict__ W,
    const float* __restrict__ bias,
    float* __restrict__ out,
    int K)
{
    __shared__ __align__(16) float As[GBK][GBM];
    __shared__ __align__(16) float Ws[GBK][GBNP];
    int tid = threadIdx.x;
    int m0 = blockIdx.x * GBM;
    int n0 = blockIdx.y * GBN;
    int lrow = tid >> 1;
    int lk = (tid & 1) * 8;
    int ty = tid >> 4;   // 0..15 (m)
    int tx = tid & 15;   // 0..15 (n)
    int wcol = lrow + 4 * ((lrow >> 5) & 1);      // swizzled write col
    int bbase = tx * 8 + 4 * ((tx >> 2) & 1);     // swizzled read base

    float acc[8][8];
    #pragma unroll
    for (int i = 0; i < 8; i++)
        #pragma unroll
        for (int j = 0; j < 8; j++) acc[i][j] = 0.f;

    for (int k0 = 0; k0 < K; k0 += GBK) {
        const float4* ap = (const float4*)(A + (size_t)(m0 + lrow) * K + k0 + lk);
        const float4* wp = (const float4*)(W + (size_t)(n0 + lrow) * K + k0 + lk);
        float4 va0 = ap[0], va1 = ap[1];
        float4 vw0 = wp[0], vw1 = wp[1];
        As[lk + 0][lrow] = va0.x; As[lk + 1][lrow] = va0.y;
        As[lk + 2][lrow] = va0.z; As[lk + 3][lrow] = va0.w;
        As[lk + 4][lrow] = va1.x; As[lk + 5][lrow] = va1.y;
        As[lk + 6][lrow] = va1.z; As[lk + 7][lrow] = va1.w;
        Ws[lk + 0][wcol] = vw0.x; Ws[lk + 1][wcol] = vw0.y;
        Ws[lk + 2][wcol] = vw0.z; Ws[lk + 3][wcol] = vw0.w;
        Ws[lk + 4][wcol] = vw1.x; Ws[lk + 5][wcol] = vw1.y;
        Ws[lk + 6][wcol] = vw1.z; Ws[lk + 7][wcol] = vw1.w;
        __syncthreads();
        #pragma unroll
        for (int k = 0; k < GBK; k++) {
            float4 a0 = *(const float4*)&As[k][ty * 8];
            float4 a1 = *(const float4*)&As[k][ty * 8 + 4];
            float4 b0 = *(const float4*)&Ws[k][bbase];
            float4 b1 = *(const float4*)&Ws[k][bbase + 4];
            float av[8] = {a0.x, a0.y, a0.z, a0.w, a1.x, a1.y, a1.z, a1.w};
            float bv[8] = {b0.x, b0.y, b0.z, b0.w, b1.x, b1.y, b1.z, b1.w};
            #pragma unroll
            for (int i = 0; i < 8; i++)
                #pragma unroll
                for (int j = 0; j < 8; j++)
                    acc[i][j] += av[i] * bv[j];
        }
        __syncthreads();
    }
    // store to xg layout: ((d*64+b)*256+t)*384 + g
    int nb = n0 + tx * 8;
    int d = nb / 384;
    int g0 = nb - d * 384;
    float bvv[8];
    #pragma unroll
    for (int j = 0; j < 8; j++) bvv[j] = bias[nb + j];
    int mbase = m0 + ty * 8;
    #pragma unroll
    for (int i = 0; i < 8; i++) {
        int m = mbase + i;
        int b = m >> 8;
        int t = m & 255;
        float* op = out + (((size_t)(d * BATCH + b) * SEQ + t) * 384 + g0);
        #pragma unroll
        for (int j = 0; j < 8; j++) op[j] = acc[i][j] + bvv[j];
    }
}

// ---------------- K4/K6: GRU recurrence, one wg per (dir, batch) ---------
// R5 structure (best: 187us, 0 conflicts): 512 threads, thread (e=i>>2,
// c=i&3) owns gate rows {e,128+e,256+e} over k-chunk [32c,32c+32), rotation
// swizzle m=(q+c)&7 -> conflict-free b128 reads, DPP quad reduction, single
// barrier/step, double-buffered h, deferred out store, xg prefetch.
// R8 change: accumulate in float2 via __builtin_elementwise_fma so the
// backend emits v_pk_fma_f32 (2 MACs/instr) — halves dot-product issue.
__global__ __launch_bounds__(512, 2) void gru_rec_k(
    const float* __restrict__ xg,    // [2][64][256][384]
    const float* __restrict__ w_hh,  // [2][384][128]
    const float* __restrict__ b_hh,  // [2][384]
    const int*   __restrict__ lens,  // [64]
    float* __restrict__ out)         // [64][256][256], channel = d*128+j
{
    int d = blockIdx.x & 1;
    int b = blockIdx.x >> 1;
    int i = threadIdx.x;   // 0..511
    int e = i >> 2;        // 0..127 hidden index
    int c = i & 3;         // 0..3 k-chunk
    __shared__ __align__(16) float hS[2][HID];

    int rR = e, rZ = HID + e, rN = 2 * HID + e;
    const float* wbR = w_hh + ((size_t)d * 384 + rR) * HID + 32 * c;
    const float* wbZ = w_hh + ((size_t)d * 384 + rZ) * HID + 32 * c;
    const float* wbN = w_hh + ((size_t)d * 384 + rN) * HID + 32 * c;
    // Preload weights in the rotated order matching the swizzled h reads
    // (iteration q consumes k-float4 m = (q + c) & 7), stored as float2
    // pairs for v_pk_fma_f32.
    float2v wR[16], wZ[16], wN[16];
    #pragma unroll
    for (int q = 0; q < 8; q++) {
        int m = (q + c) & 7;
        float4 tR = *(const float4*)(wbR + 4 * m);
        float4 tZ = *(const float4*)(wbZ + 4 * m);
        float4 tN = *(const float4*)(wbN + 4 * m);
        wR[2 * q].x = tR.x; wR[2 * q].y = tR.y; wR[2 * q + 1].x = tR.z; wR[2 * q + 1].y = tR.w;
        wZ[2 * q].x = tZ.x; wZ[2 * q].y = tZ.y; wZ[2 * q + 1].x = tZ.z; wZ[2 * q + 1].y = tZ.w;
        wN[2 * q].x = tN.x; wN[2 * q].y = tN.y; wN[2 * q + 1].x = tN.z; wN[2 * q + 1].y = tN.w;
    }
    float bhR = b_hh[d * 384 + rR];
    float bhZ = b_hh[d * 384 + rZ];
    float bhN = b_hh[d * 384 + rN];
    int len = lens[b];

    if (i < HID) hS[0][i] = 0.f;
    float hold = 0.f;
    __syncthreads();

    const float* xgb = xg + ((size_t)(d * BATCH + b)) * SEQ * 384;
    float* outb = out + (size_t)b * SEQ * 256 + d * HID;

    int t0 = d ? (SEQ - 1) : 0;
    float xvR = xgb[(size_t)t0 * 384 + rR];
    float xvZ = xgb[(size_t)t0 * 384 + rZ];
    float xvN = xgb[(size_t)t0 * 384 + rN];
    int tPrev = 0;

    for (int s = 0; s < SEQ; s++) {
        int t = d ? (SEQ - 1 - s) : s;
        // deferred out-store of the previous step's h (vmcnt drain hidden
        // behind this step's dot-product work)
        if (s && c == 0) outb[(size_t)tPrev * 256 + e] = hold;
        // prefetch next step's xg
        int sn = (s + 1 < SEQ) ? (s + 1) : s;
        int tn = d ? (SEQ - 1 - sn) : sn;
        float nxvR = xgb[(size_t)tn * 384 + rR];
        float nxvZ = xgb[(size_t)tn * 384 + rZ];
        float nxvN = xgb[(size_t)tn * 384 + rN];

        const float4* hb = (const float4*)hS[s & 1] + 8 * c;
        float2v aR = {0.f, 0.f}, aZ = {0.f, 0.f}, aN = {0.f, 0.f};
        #pragma unroll
        for (int q = 0; q < 8; q++) {
            int m = (q + c) & 7;
            float4 hv = hb[m];
            float2v hlo; hlo.x = hv.x; hlo.y = hv.y;
            float2v hhi; hhi.x = hv.z; hhi.y = hv.w;
            aR = __builtin_elementwise_fma(wR[2 * q], hlo, aR);
            aR = __builtin_elementwise_fma(wR[2 * q + 1], hhi, aR);
            aZ = __builtin_elementwise_fma(wZ[2 * q], hlo, aZ);
            aZ = __builtin_elementwise_fma(wZ[2 * q + 1], hhi, aZ);
            aN = __builtin_elementwise_fma(wN[2 * q], hlo, aN);
            aN = __builtin_elementwise_fma(wN[2 * q + 1], hhi, aN);
        }
        float sR = quad_sum(aR.x + aR.y);
        float sZ = quad_sum(aZ.x + aZ.y);
        float sN = quad_sum(aN.x + aN.y);

        float r = sigm(xvR + sR + bhR);
        float z = sigm(xvZ + sZ + bhZ);
        float n = tanh_fast(xvN + r * (sN + bhN));
        float hnew = (1.f - z) * n + z * hold;
        hold = (t < len) ? hnew : hold;
        if (c == 0) hS[(s & 1) ^ 1][e] = hold;
        tPrev = t;
        xvR = nxvR; xvZ = nxvZ; xvN = nxvN;
        __syncthreads();
    }
    if (c == 0) outb[(size_t)tPrev * 256 + e] = hold;
}

// ---------------- K7: MLP (relu) + emissions -----------------------------
__global__ __launch_bounds__(128) void mlp_emis_k(
    const float* __restrict__ h1,    // [16384][256]
    const float* __restrict__ w1,    // [256][128]
    const float* __restrict__ b1,    // [128]
    const float* __restrict__ w2,    // [128][17]
    const float* __restrict__ b2,    // [17]
    float* __restrict__ emis)        // [16384][17]
{
    __shared__ __align__(16) float hrow[8 * 256];
    __shared__ float hid[8][HID];
    int p0 = blockIdx.x * 8;
    int tid = threadIdx.x;
    for (int e = tid; e < 8 * 256; e += 128)
        hrow[e] = h1[(size_t)p0 * 256 + e];
    __syncthreads();
    float acc[8];
    float bb = b1[tid];
    #pragma unroll
    for (int i = 0; i < 8; i++) acc[i] = bb;
    for (int k = 0; k < 256; k++) {
        float wv = w1[k * HID + tid];
        #pragma unroll
        for (int i = 0; i < 8; i++) acc[i] += hrow[i * 256 + k] * wv;
    }
    #pragma unroll
    for (int i = 0; i < 8; i++) hid[i][tid] = fmaxf(acc[i], 0.f);
    __syncthreads();
    for (int idx = tid; idx < 8 * NT; idx += 128) {
        int pos = idx / NT;
        int tg = idx - pos * NT;
        float a = b2[tg];
        for (int k = 0; k < HID; k++) a += hid[pos][k] * w2[k * NT + tg];
        emis[(size_t)(p0 + pos) * NT + tg] = a;
    }
}

// ---------------- K8: CRF score + forward algorithm ----------------------
__global__ __launch_bounds__(64) void crf_k(
    const float* __restrict__ emis,   // [64][256][17]
    const float* __restrict__ start,
    const float* __restrict__ endv,
    const float* __restrict__ trans,  // [17][17]
    const int*   __restrict__ target, // [64][256]
    const int*   __restrict__ lens,
    float* __restrict__ llh)          // [64]
{
    int b = blockIdx.x;
    int tid = threadIdx.x;
    __shared__ float tr[NT * NT];
    __shared__ float aSh[NT];
    __shared__ float scoreSh;
    for (int e = tid; e < NT * NT; e += 64) tr[e] = trans[e];
    __syncthreads();
    int len = lens[b];
    const int* tgt = target + b * SEQ;
    const float* eb = emis + (size_t)b * SEQ * NT;

    // gold score (parallel over t, reduce in-wave)
    float part = 0.f;
    for (int t = 1 + tid; t < SEQ; t += 64) {
        if (t < len) {
            int tp = tgt[t - 1], tc = tgt[t];
            part += tr[tp * NT + tc] + eb[(size_t)t * NT + tc];
        }
    }
    #pragma unroll
    for (int off = 32; off > 0; off >>= 1)
        part += __shfl_down(part, off, 64);
    if (tid == 0) {
        int t0 = tgt[0];
        scoreSh = part + start[t0] + eb[t0] + endv[tgt[len - 1]];
    }

    // forward algorithm
    float a = (tid < NT) ? (start[tid] + eb[tid]) : 0.f;
    for (int t = 1; t < SEQ; t++) {
        if (tid < NT) aSh[tid] = a;
        __syncthreads();
        if (t < len && tid < NT) {
            float m = -1e30f;
            #pragma unroll
            for (int i = 0; i < NT; i++)
                m = fmaxf(m, aSh[i] + tr[i * NT + tid]);
            float ssum = 0.f;
            #pragma unroll
            for (int i = 0; i < NT; i++)
                ssum += __expf(aSh[i] + tr[i * NT + tid] - m);
            a = m + __logf(ssum) + eb[(size_t)t * NT + tid];
        }
        __syncthreads();
    }
    float v = (tid < NT) ? (a + endv[tid]) : -1e30f;
    float m = v;
    #pragma unroll
    for (int off = 32; off > 0; off >>= 1)
        m = fmaxf(m, __shfl_down(m, off, 64));
    m = __shfl(m, 0, 64);
    float e = (tid < NT) ? __expf(v - m) : 0.f;
    #pragma unroll
    for (int off = 32; off > 0; off >>= 1)
        e += __shfl_down(e, off, 64);
    if (tid == 0) {
        float logz = m + __logf(e);
        llh[b] = scoreSh - logz;
    }
}

// ---------------- K9: final loss -----------------------------------------
__global__ __launch_bounds__(64) void finalize_k(
    const float* __restrict__ llh,
    const int*   __restrict__ lens,
    float* __restrict__ out)
{
    int tid = threadIdx.x;
    float s = llh[tid];
    float lf = (float)lens[tid];
    #pragma unroll
    for (int off = 32; off > 0; off >>= 1) {
        s += __shfl_down(s, off, 64);
        lf += __shfl_down(lf, off, 64);
    }
    if (tid == 0) out[0] = -(s / lf);
}

extern "C" void kernel_launch(void* const* d_in, const int* in_sizes, int n_in,
                              void* d_out, int out_size, void* d_ws, size_t ws_size,
                              hipStream_t stream) {
    const float* char_emb = (const float*)d_in[0];
    const float* conv_w   = (const float*)d_in[1];
    const float* conv_b   = (const float*)d_in[2];
    const float* word_emb = (const float*)d_in[3];
    const float* w_ih_l0  = (const float*)d_in[4];
    const float* w_hh_l0  = (const float*)d_in[5];
    const float* b_ih_l0  = (const float*)d_in[6];
    const float* b_hh_l0  = (const float*)d_in[7];
    const float* w_ih_l1  = (const float*)d_in[8];
    const float* w_hh_l1  = (const float*)d_in[9];
    const float* b_ih_l1  = (const float*)d_in[10];
    const float* b_hh_l1  = (const float*)d_in[11];
    const float* mlp_w1   = (const float*)d_in[12];
    const float* mlp_b1   = (const float*)d_in[13];
    const float* mlp_w2   = (const float*)d_in[14];
    const float* mlp_b2   = (const float*)d_in[15];
    const float* crf_start= (const float*)d_in[16];
    const float* crf_end  = (const float*)d_in[17];
    const float* crf_trans= (const float*)d_in[18];
    const int* bcw   = (const int*)d_in[19];
    // d_in[20] batched_char_words_len: unused by reference
    const int* bcwi  = (const int*)d_in[21];
    const int* btok  = (const int*)d_in[22];
    const int* blen  = (const int*)d_in[23];
    const int* target= (const int*)d_in[24];

    float* ws    = (float*)d_ws;
    float* xg    = ws + OFF_XG;
    float* texts = ws + OFF_TEXTS;   // aliased: h0 overwrites texts after xg0 GEMM
    float* h0    = texts;
    float* h1    = ws + OFF_H1;
    float* tok   = ws + OFF_TOK;
    float* emis  = ws + OFF_EMIS;
    float* wpad  = ws + OFF_WPAD;
    float* llh   = ws + OFF_LLH;

    hipMemsetAsync(tok, 0, CDIM * sizeof(float), stream);  // tok_enc row 0 = zeros
    pad_w_k<<<768, 64, 0, stream>>>(w_ih_l0, wpad);
    char_conv_k<<<NW / 8, 256, 0, stream>>>(char_emb, conv_w, conv_b, bcw, tok);
    build_texts_k<<<NPOS, 128, 0, stream>>>(word_emb, tok, btok, bcwi, texts);
    gemm_xg_k<<<dim3(NPOS / GBM, 768 / GBN), 256, 0, stream>>>(texts, wpad, b_ih_l0, xg, IN0P);
    gru_rec_k<<<2 * BATCH, 512, 0, stream>>>(xg, w_hh_l0, b_hh_l0, blen, h0);
    gemm_xg_k<<<dim3(NPOS / GBM, 768 / GBN), 256, 0, stream>>>(h0, w_ih_l1, b_ih_l1, xg, IN1);
    gru_rec_k<<<2 * BATCH, 512, 0, stream>>>(xg, w_hh_l1, b_hh_l1, blen, h1);
    mlp_emis_k<<<NPOS / 8, 128, 0, stream>>>(h1, mlp_w1, mlp_b1, mlp_w2, mlp_b2, emis);
    crf_k<<<BATCH, 64, 0, stream>>>(emis, crf_start, crf_end, crf_trans, target, blen, llh);
    finalize_k<<<1, 64, 0, stream>>>(llh, blen, (float*)d_out);
}